// Round 4
// baseline (79.098 us; speedup 1.0000x reference)
//
#include <hip/hip_runtime.h>

// FidelityKernel: K[i,j] = |perm( (U2[j][:, :6])^H @ (U1[i][:, :6]) )|^2 / 1024
// Two lanes per pair: lane h accumulates W over k in [6h, 6h+6), partners merge
// via shfl_xor(1) (DPP), then each lane runs 2 of 4 Gray-code Glynn chains.
// Complex math on float2 ext-vectors -> v_pk_fma_f32.

typedef float v2f __attribute__((ext_vector_type(2)));

#define NS 384      // samples per side
#define MM 12       // modes
#define NP 6        // photons (submatrix size)
#define TSJ 16      // j-tile (columns of out)
#define TSI 8       // i-tile (rows of out); 16x8 pairs x 2 lanes = 256 threads
#define SV_STRIDE 148  // 144 payload floats + 4 pad

__device__ __forceinline__ v2f cmul(v2f a, v2f b) {
    v2f r = (v2f){a.x, a.x} * b;
    return __builtin_elementwise_fma((v2f){a.y, a.y}, (v2f){-b.y, b.x}, r);
}
__device__ __forceinline__ v2f cmac(v2f acc, v2f a, v2f b) {
    acc = __builtin_elementwise_fma((v2f){a.x, a.x}, b, acc);
    return __builtin_elementwise_fma((v2f){a.y, a.y}, (v2f){-b.y, b.x}, acc);
}

// V1[s][k][c] = U1(x1_s)[k,c], V2c[s][k][c] = conj(U2(x2_s)[k,c]), c<6.
// One thread per (half, s, a, c) -> 55296 threads.
__global__ void build_V_kernel(const float* __restrict__ x1,
                               const float* __restrict__ x2,
                               const float* __restrict__ Ar, const float* __restrict__ Ai,
                               const float* __restrict__ Br, const float* __restrict__ Bi,
                               float* __restrict__ V1, float* __restrict__ V2c) {
    int idx = blockIdx.x * blockDim.x + threadIdx.x;
    if (idx >= 2 * NS * MM * NP) return;
    int c = idx % NP;  int rest = idx / NP;
    int a = rest % MM; rest /= MM;
    int s = rest % NS; int half = rest / NS;
    const float* x = half ? x2 : x1;

    v2f u = {0.f, 0.f};
#pragma unroll
    for (int b = 0; b < MM; ++b) {
        float sv, cv;
        __sincosf(x[s * MM + b], &sv, &cv);   // hw v_sin/v_cos; x ~ N(0,1)
        v2f ph = {cv, sv};
        v2f Bv = {Br[b * MM + c], Bi[b * MM + c]};
        v2f t  = cmul(ph, Bv);
        v2f Av = {Ar[a * MM + b], Ai[a * MM + b]};
        u = cmac(u, Av, t);
    }
    float* V = half ? V2c : V1;
    int off = ((s * MM + a) * NP + c) * 2;
    V[off]     = u.x;
    V[off + 1] = half ? -u.y : u.y;   // conjugate U2 at store time
}

__device__ __forceinline__ v2f tree_prod(const v2f rs[NP]) {
    v2f p01 = cmul(rs[0], rs[1]);
    v2f p23 = cmul(rs[2], rs[3]);
    v2f p45 = cmul(rs[4], rs[5]);
    return cmul(cmul(p01, p23), p45);
}

// Block = 16x8 pairs x 2 lanes. LDS stages 8 V1 rows + 16 V2 rows.
__global__ __launch_bounds__(256, 4) void perm_kernel(const float* __restrict__ V1g,
                                                      const float* __restrict__ V2g,
                                                      float* __restrict__ out) {
    __shared__ __align__(16) float sV1[TSI * SV_STRIDE];
    __shared__ __align__(16) float sV2[TSJ * SV_STRIDE];
    const int i0 = blockIdx.y * TSI;
    const int j0 = blockIdx.x * TSJ;
    const int tid = threadIdx.x;

    // Stage (8 + 16) samples x 144 floats (36 float4 each).
    for (int idx = tid; idx < (TSI + TSJ) * 36; idx += 256) {
        int which = idx >= TSI * 36;                 // 0: V1, 1: V2
        int rem = which ? idx - TSI * 36 : idx;
        int s = rem / 36, q = rem - s * 36;
        const float* src = which ? (V2g + (j0 + s) * 144) : (V1g + (i0 + s) * 144);
        float4 v = *(const float4*)(src + q * 4);
        float* dst = (which ? sV2 : sV1) + s * SV_STRIDE + q * 4;
        *(float4*)dst = v;
    }
    __syncthreads();

    const int h  = tid & 1;        // k-half / s4 bit
    const int p  = tid >> 1;       // pair id 0..127
    const int tx = p & 15;         // j within tile
    const int ty = p >> 4;         // i within tile (0..7)
    const float* v1 = sV1 + ty * SV_STRIDE;
    const float* v2 = sV2 + tx * SV_STRIDE;

    // Partial W over this lane's k-half: W[a][b] += conj(U2)[k,a] * U1[k,b]
    v2f W[NP][NP];
#pragma unroll
    for (int a = 0; a < NP; ++a)
#pragma unroll
        for (int b = 0; b < NP; ++b) W[a][b] = (v2f){0.f, 0.f};

#pragma unroll
    for (int kk = 0; kk < NP; ++kk) {
        const int k = h * NP + kk;               // uniform-per-lane offset
        const v2f* c1 = (const v2f*)(v1 + k * 12);
        const v2f* c2 = (const v2f*)(v2 + k * 12);
        v2f a1[NP], a2[NP];
#pragma unroll
        for (int b = 0; b < NP; ++b) { a1[b] = c1[b]; a2[b] = c2[b]; }
#pragma unroll
        for (int a = 0; a < NP; ++a)
#pragma unroll
            for (int b = 0; b < NP; ++b)
                W[a][b] = cmac(W[a][b], a2[a], a1[b]);
    }

    // Merge k-halves with partner lane (lane ^ 1): W_full = W_me + W_partner.
#pragma unroll
    for (int a = 0; a < NP; ++a)
#pragma unroll
        for (int b = 0; b < NP; ++b) {
            v2f w = W[a][b];
            w.x += __shfl_xor(w.x, 1);
            w.y += __shfl_xor(w.y, 1);
            W[a][b] = w;
        }

    // Glynn: delta_0=+1; bits s_0..s_4 <-> delta_1..delta_5.
    // s_4 = h (this lane), s_3 = chain index; Gray-code s_0..s_2 (rows 1..3).
    v2f base[NP];
#pragma unroll
    for (int b = 0; b < NP; ++b) {
        base[b] = W[0][b];
#pragma unroll
        for (int a = 1; a < NP; ++a) base[b] += W[a][b];
    }

    const float hf = -2.f * (float)h;   // 0 or -2
    v2f rs[2][NP];
#pragma unroll
    for (int b = 0; b < NP; ++b) {
        v2f r0 = __builtin_elementwise_fma((v2f){hf, hf}, W[5][b], base[b]);  // s4=h
        rs[0][b] = r0;                                                        // s3=0
        rs[1][b] = __builtin_elementwise_fma((v2f){-2.f, -2.f}, W[4][b], r0); // s3=1
    }

    v2f acc[2];
#pragma unroll
    for (int ch = 0; ch < 2; ++ch) acc[ch] = tree_prod(rs[ch]);

    unsigned st = 0;  // Gray state of s_0..s_2
#pragma unroll
    for (int u = 1; u < 8; ++u) {
        const int bitpos = __builtin_ctz(u);   // compile-time after unroll
        const int r = bitpos + 1;              // row flipped (rows 1..3)
        float cf = ((st >> bitpos) & 1) ? 2.f : -2.f;
        st ^= (1u << bitpos);
        float sgn_u = (u & 1) ? -1.f : 1.f;    // (-1)^popcount(gray(u))
        v2f cfv = {cf, cf};
        v2f sgv = {sgn_u, sgn_u};
#pragma unroll
        for (int ch = 0; ch < 2; ++ch) {
#pragma unroll
            for (int b = 0; b < NP; ++b)
                rs[ch][b] = __builtin_elementwise_fma(cfv, W[r][b], rs[ch][b]);
            v2f pr = tree_prod(rs[ch]);
            acc[ch] = __builtin_elementwise_fma(sgv, pr, acc[ch]);
        }
    }

    // lane parity (-1)^h on (acc_s3=0 - acc_s3=1), then sum the two lanes.
    float psgn = h ? -1.f : 1.f;
    v2f at = (acc[0] - acc[1]) * (v2f){psgn, psgn};
    at.x += __shfl_xor(at.x, 1);
    at.y += __shfl_xor(at.y, 1);

    if (h == 0) {
        // perm = at / 32; K = |perm|^2
        float K = fmaf(at.x, at.x, at.y * at.y) * (1.f / 1024.f);
        out[(i0 + ty) * NS + (j0 + tx)] = K;
    }
}

extern "C" void kernel_launch(void* const* d_in, const int* in_sizes, int n_in,
                              void* d_out, int out_size, void* d_ws, size_t ws_size,
                              hipStream_t stream) {
    const float* x1 = (const float*)d_in[0];
    const float* x2 = (const float*)d_in[1];
    const float* Ar = (const float*)d_in[2];
    const float* Ai = (const float*)d_in[3];
    const float* Br = (const float*)d_in[4];
    const float* Bi = (const float*)d_in[5];
    float* out = (float*)d_out;

    float* V1  = (float*)d_ws;                  // 384*12*6*2 floats
    float* V2c = V1 + NS * MM * NP * 2;

    int total = 2 * NS * MM * NP;  // 55296 threads
    build_V_kernel<<<(total + 255) / 256, 256, 0, stream>>>(x1, x2, Ar, Ai, Br, Bi, V1, V2c);

    dim3 grid(NS / TSJ, NS / TSI);  // 24 x 48
    perm_kernel<<<grid, 256, 0, stream>>>(V1, V2c, out);
}

// Round 5
// 78.050 us; speedup vs baseline: 1.0134x; 1.0134x over previous
//
#include <hip/hip_runtime.h>

// FidelityKernel: K[i,j] = |perm( (U2[j][:, :6])^H @ (U1[i][:, :6]) )|^2 / 1024
// Single fused kernel: each block builds the V-slices it needs (U cols 0..5)
// directly into LDS (threads 0..191: one (sample, column) gemv each), then
// one thread per pair runs the 6x6 complex W-build + Glynn permanent via
// 4 independent Gray-code chains. Complex math on float2 -> v_pk_fma_f32.

typedef float v2f __attribute__((ext_vector_type(2)));

#define NS 384      // samples per side
#define MM 12       // modes
#define NP 6        // photons (submatrix size)
#define TS 16       // pair-tile edge (16x16 pairs per block = 256 threads)
#define SV_STRIDE 148  // 144 payload floats + 4 pad

__device__ __forceinline__ v2f cmul(v2f a, v2f b) {
    v2f r = (v2f){a.x, a.x} * b;
    return __builtin_elementwise_fma((v2f){a.y, a.y}, (v2f){-b.y, b.x}, r);
}
__device__ __forceinline__ v2f cmac(v2f acc, v2f a, v2f b) {
    acc = __builtin_elementwise_fma((v2f){a.x, a.x}, b, acc);
    return __builtin_elementwise_fma((v2f){a.y, a.y}, (v2f){-b.y, b.x}, acc);
}

__device__ __forceinline__ v2f tree_prod(const v2f rs[NP]) {
    v2f p01 = cmul(rs[0], rs[1]);
    v2f p23 = cmul(rs[2], rs[3]);
    v2f p45 = cmul(rs[4], rs[5]);
    return cmul(cmul(p01, p23), p45);
}

__global__ __launch_bounds__(256) void fused_kernel(const float* __restrict__ x1,
                                                    const float* __restrict__ x2,
                                                    const float* __restrict__ Ar,
                                                    const float* __restrict__ Ai,
                                                    const float* __restrict__ Br,
                                                    const float* __restrict__ Bi,
                                                    float* __restrict__ out) {
    __shared__ __align__(16) float sV1[TS * SV_STRIDE];
    __shared__ __align__(16) float sV2[TS * SV_STRIDE];
    const int i0 = blockIdx.y * TS;
    const int j0 = blockIdx.x * TS;
    const int tid = threadIdx.x;

    // ---- Phase 1: build V-slices into LDS. 32 samples x 6 columns = 192 jobs.
    // sV1[r][k][c] = U1(x1_{i0+r})[k,c]; sV2[r][k][c] = conj(U2(x2_{j0+r}))[k,c]
    if (tid < 2 * TS * NP) {
        int sm = tid / NP, c = tid - sm * NP;
        int half = sm >= TS;
        int s = half ? (j0 + sm - TS) : (i0 + sm);
        const float* x = half ? x2 : x1;

        // t[b] = e^{i x[s,b]} * B[b,c]
        v2f t[MM];
#pragma unroll
        for (int b = 0; b < MM; ++b) {
            float sv, cv;
            __sincosf(x[s * MM + b], &sv, &cv);   // hw v_sin/v_cos; x ~ N(0,1)
            v2f Bv = {Br[b * MM + c], Bi[b * MM + c]};
            t[b] = cmul((v2f){cv, sv}, Bv);
        }

        float* dst = (half ? sV2 : sV1) + (sm & (TS - 1)) * SV_STRIDE;
        float sgn = half ? -1.f : 1.f;   // conjugate U2 at store time
#pragma unroll
        for (int a = 0; a < MM; ++a) {
            v2f u = {0.f, 0.f};
#pragma unroll
            for (int b = 0; b < MM; ++b) {
                // A indices are wave-uniform -> scalar loads
                v2f Av = {Ar[a * MM + b], Ai[a * MM + b]};
                u = cmac(u, Av, t[b]);
            }
            dst[(a * NP + c) * 2]     = u.x;
            dst[(a * NP + c) * 2 + 1] = sgn * u.y;
        }
    }
    __syncthreads();

    // ---- Phase 2: one thread per (i,j) pair.
    const int tx = tid & 15, ty = tid >> 4;
    const float* v1 = sV1 + ty * SV_STRIDE;  // broadcast across tx lanes
    const float* v2 = sV2 + tx * SV_STRIDE;  // 2-way max aliasing (free)

    // W[a][b] = sum_k conj(U2[j,k,a]) * U1[i,k,b]  (conj baked into sV2)
    v2f W[NP][NP];
#pragma unroll
    for (int a = 0; a < NP; ++a)
#pragma unroll
        for (int b = 0; b < NP; ++b) W[a][b] = (v2f){0.f, 0.f};

#pragma unroll
    for (int k = 0; k < MM; ++k) {
        const v2f* c1 = (const v2f*)(v1 + k * 12);
        const v2f* c2 = (const v2f*)(v2 + k * 12);
        v2f a1[NP], a2[NP];
#pragma unroll
        for (int b = 0; b < NP; ++b) { a1[b] = c1[b]; a2[b] = c2[b]; }
#pragma unroll
        for (int a = 0; a < NP; ++a)
#pragma unroll
            for (int b = 0; b < NP; ++b)
                W[a][b] = cmac(W[a][b], a2[a], a1[b]);
    }

    // Glynn: delta_0 = +1; bits s_0..s_4 <-> delta_1..delta_5.
    // Split on (s_3, s_4) -> 4 independent chains Gray-coding s_0..s_2.
    v2f base[NP];
#pragma unroll
    for (int b = 0; b < NP; ++b) {
        base[b] = W[0][b];
#pragma unroll
        for (int a = 1; a < NP; ++a) base[b] += W[a][b];
    }

    v2f rs[4][NP];
#pragma unroll
    for (int b = 0; b < NP; ++b) {
        v2f m2 = {-2.f, -2.f};
        rs[0][b] = base[b];
        rs[1][b] = __builtin_elementwise_fma(m2, W[4][b], base[b]);   // delta_4 = -1
        rs[2][b] = __builtin_elementwise_fma(m2, W[5][b], base[b]);   // delta_5 = -1
        rs[3][b] = __builtin_elementwise_fma(m2, W[5][b], rs[1][b]);  // both
    }
    // chain parity at u=0: (-1)^{s3+s4} = {+1, -1, -1, +1}
    v2f acc[4];
#pragma unroll
    for (int ch = 0; ch < 4; ++ch) acc[ch] = tree_prod(rs[ch]);

    unsigned st = 0;  // Gray state of s_0..s_2 (shared by all chains)
#pragma unroll
    for (int u = 1; u < 8; ++u) {
        const int bitpos = __builtin_ctz(u);   // compile-time after unroll
        const int r = bitpos + 1;              // row flipped (rows 1..3)
        float cf = ((st >> bitpos) & 1) ? 2.f : -2.f;
        st ^= (1u << bitpos);
        float sgn_u = (u & 1) ? -1.f : 1.f;    // (-1)^popcount(gray(u))
        v2f cfv = {cf, cf};
        v2f sgv = {sgn_u, sgn_u};
#pragma unroll
        for (int ch = 0; ch < 4; ++ch) {
#pragma unroll
            for (int b = 0; b < NP; ++b)
                rs[ch][b] = __builtin_elementwise_fma(cfv, W[r][b], rs[ch][b]);
            v2f p = tree_prod(rs[ch]);
            acc[ch] = __builtin_elementwise_fma(sgv, p, acc[ch]);
        }
    }

    v2f aa = acc[0] - acc[1] - acc[2] + acc[3];
    // perm = aa / 32; K = |perm|^2
    float K = fmaf(aa.x, aa.x, aa.y * aa.y) * (1.f / 1024.f);
    out[(i0 + ty) * NS + (j0 + tx)] = K;
}

extern "C" void kernel_launch(void* const* d_in, const int* in_sizes, int n_in,
                              void* d_out, int out_size, void* d_ws, size_t ws_size,
                              hipStream_t stream) {
    const float* x1 = (const float*)d_in[0];
    const float* x2 = (const float*)d_in[1];
    const float* Ar = (const float*)d_in[2];
    const float* Ai = (const float*)d_in[3];
    const float* Br = (const float*)d_in[4];
    const float* Bi = (const float*)d_in[5];
    float* out = (float*)d_out;
    (void)d_ws; (void)ws_size;

    dim3 grid(NS / TS, NS / TS);  // 24 x 24, single kernel
    fused_kernel<<<grid, 256, 0, stream>>>(x1, x2, Ar, Ai, Br, Bi, out);
}